// Round 10
// baseline (132.526 us; speedup 1.0000x reference)
//
#include <hip/hip_runtime.h>

// LoRA: out = x @ (A@B) * 1.0, computed as (x@A)@B, FUSED in one kernel.
// x: [M=16384, K=4096] f32, A: [K, 16] f32, B: [16, N=4096] f32.
// Phase 1 (per block of 16 rows): T-tile = x-rows @ A  (r2 compute body),
//   with A-chunks double-buffered in LDS via async global_load_lds (T3
//   minimum-2-phase: stage c+1 issued before compute of c; the end-of-chunk
//   barrier's vmcnt drain completes it for free). Zero staging VGPRs.
// Phase 2: out-rows = T-tile @ B (r9's, at the write roofline).
constexpr int RANK = 16;
constexpr int K = 4096;
constexpr int N = 4096;
constexpr int M = 4 * 4096;
constexpr int KC = 256;          // K-chunk (16 KB per LDS buffer)
constexpr int NCHUNK = K / KC;   // 16

typedef const __attribute__((address_space(1))) void gv_t;
typedef __attribute__((address_space(3))) void lds_t;

__global__ __launch_bounds__(256) void lora_fused(const float* __restrict__ x,
                                                  const float* __restrict__ A,
                                                  const float* __restrict__ B,
                                                  float* __restrict__ out) {
  const int lane = threadIdx.x & 63;
  const int tid = threadIdx.x;
  const int wave = tid >> 6;
  const int rbase = blockIdx.x * 16;
  const int r0 = rbase + wave * 4;  // this wave's 4 rows (phase 1)
  const int m = (lane >> 2) & 3;

  __shared__ float4 As[2][KC * 4];  // 2 x 16 KB, swizzled A chunks
  __shared__ float Ts[16][RANK];    // 1 KB, block's T-tile

  const float4* __restrict__ A4 = reinterpret_cast<const float4*>(A);

  // ---- async stage of chunk cc into buffer b (global_load_lds width=16).
  // LDS layout = r2's swizzle (slot s of row k at p = s ^ ((k>>2)&3)),
  // realized by PRE-SWIZZLING the per-lane GLOBAL source (guide rule 21):
  // LDS slot n receives global slot g(n) = (n&~3) | ((n&3) ^ ((n>>4)&3)).
  // LDS dest is wave-uniform base + lane*16 (linear), as HW requires.
#define STAGE(b, cc)                                                        \
  {                                                                         \
    _Pragma("unroll")                                                       \
    for (int q = 0; q < 4; ++q) {                                           \
      const int nbase = q * 256 + wave * 64;                                \
      const int n = nbase + lane;                                           \
      const int g = (n & ~3) | ((n & 3) ^ ((n >> 4) & 3));                  \
      __builtin_amdgcn_global_load_lds(                                     \
          (gv_t*)(A4 + (size_t)(cc) * (KC * 4) + g),                        \
          (lds_t*)&As[b][nbase], 16, 0, 0);                                 \
    }                                                                       \
  }

  // ================= Phase 1: T-tile = x @ A =============
  float vals[64];
#pragma unroll
  for (int i = 0; i < 64; ++i) vals[i] = 0.0f;

  STAGE(0, 0)
  __syncthreads();  // vmcnt drained -> chunk 0 resident

  for (int c = 0; c < NCHUNK; ++c) {
    const int cur = c & 1;
    if (c + 1 < NCHUNK) STAGE(cur ^ 1, c + 1)  // overlaps this chunk's compute

    const float4* __restrict__ buf = As[cur];

    // ---- compute: 4 k-blocks of 64 (one k per lane), r2 body ----
#pragma unroll
    for (int kbi = 0; kbi < KC / 64; ++kbi) {
      const int kl = kbi * 64 + lane;           // local k in chunk
      const size_t kg = (size_t)c * KC + kl;    // global k

      float xv[4];
#pragma unroll
      for (int r = 0; r < 4; ++r) xv[r] = x[(size_t)(r0 + r) * K + kg];

      float4 a[4];
#pragma unroll
      for (int s = 0; s < 4; ++s) a[s] = buf[kl * 4 + (s ^ m)];

#pragma unroll
      for (int r = 0; r < 4; ++r) {
#pragma unroll
        for (int s = 0; s < 4; ++s) {
          vals[r * 16 + 4 * s + 0] = fmaf(xv[r], a[s].x, vals[r * 16 + 4 * s + 0]);
          vals[r * 16 + 4 * s + 1] = fmaf(xv[r], a[s].y, vals[r * 16 + 4 * s + 1]);
          vals[r * 16 + 4 * s + 2] = fmaf(xv[r], a[s].z, vals[r * 16 + 4 * s + 2]);
          vals[r * 16 + 4 * s + 3] = fmaf(xv[r], a[s].w, vals[r * 16 + 4 * s + 3]);
        }
      }
    }
    __syncthreads();  // readers of buf[cur] done; stage(c+1) drained
  }
#undef STAGE

  // Reduce-scatter (proven): lane i ends with element i (r=i>>4, j=i&15).
#define RSTEP(HALF)                                            \
  {                                                            \
    const bool hi = (lane & (HALF)) != 0;                      \
    _Pragma("unroll")                                          \
    for (int i = 0; i < (HALF); ++i) {                         \
      const float send = hi ? vals[i] : vals[i + (HALF)];      \
      const float keep = hi ? vals[i + (HALF)] : vals[i];      \
      vals[i] = keep + __shfl_xor(send, (HALF), 64);           \
    }                                                          \
  }
  RSTEP(32)
  RSTEP(16)
  RSTEP(8)
  RSTEP(4)
  RSTEP(2)
  RSTEP(1)
#undef RSTEP

  // Hand off T-tile via LDS (1 write/lane, conflict-free).
  Ts[wave * 4 + (lane >> 4)][lane & 15] = vals[0];
  __syncthreads();

  // ================= Phase 2: out-tile = T-tile @ B (r9, proven) ==========
  const float4* __restrict__ B4 = reinterpret_cast<const float4*>(B);
  float4* __restrict__ out4 = reinterpret_cast<float4*>(out);

#pragma unroll 1
  for (int cc = 0; cc < 4; ++cc) {
    const int col = wave * 1024 + cc * 256 + lane * 4;

    float4 b[16];
#pragma unroll
    for (int j = 0; j < RANK; ++j) b[j] = B4[((size_t)j * N + col) >> 2];

#pragma unroll 1
    for (int r = 0; r < 16; ++r) {
      // Broadcast T row r (same addr all lanes -> free LDS broadcast).
      const float4* __restrict__ tr4 =
          reinterpret_cast<const float4*>(&Ts[r][0]);
      const float4 t0 = tr4[0];
      const float4 t1 = tr4[1];
      const float4 t2 = tr4[2];
      const float4 t3 = tr4[3];

      float4 acc;
      acc.x = acc.y = acc.z = acc.w = 0.0f;
      const float tsv[16] = {t0.x, t0.y, t0.z, t0.w, t1.x, t1.y, t1.z, t1.w,
                             t2.x, t2.y, t2.z, t2.w, t3.x, t3.y, t3.z, t3.w};
#pragma unroll
      for (int j = 0; j < RANK; ++j) {
        acc.x = fmaf(tsv[j], b[j].x, acc.x);
        acc.y = fmaf(tsv[j], b[j].y, acc.y);
        acc.z = fmaf(tsv[j], b[j].z, acc.z);
        acc.w = fmaf(tsv[j], b[j].w, acc.w);
      }
      out4[((size_t)(rbase + r) * N + col) >> 2] = acc;
    }
  }
}

extern "C" void kernel_launch(void* const* d_in, const int* in_sizes, int n_in,
                              void* d_out, int out_size, void* d_ws, size_t ws_size,
                              hipStream_t stream) {
  const float* x = (const float*)d_in[0];   // [M, K]
  const float* A = (const float*)d_in[1];   // [K, RANK]
  const float* B = (const float*)d_in[2];   // [16, N]
  float* out = (float*)d_out;               // [M, N]
  (void)d_ws; (void)ws_size;

  // One fused kernel: 16 rows per block -> 1024 blocks.
  lora_fused<<<M / 16, 256, 0, stream>>>(x, A, B, out);
}